// Round 16
// baseline (409.962 us; speedup 1.0000x reference)
//
#include <hip/hip_runtime.h>
#include <cstdint>
#include <cstddef>

typedef unsigned short u16;
typedef __attribute__((ext_vector_type(8))) short short8v;
typedef __attribute__((ext_vector_type(4))) float f32x4;

#define IN_DIM 128
#define HID_DIM 256
#define OUT_DIM 128
#define HEADS 4

__device__ __forceinline__ float b2f(u16 v) {
    return __uint_as_float(((unsigned)v) << 16);
}
__device__ __forceinline__ u16 f2b(float f) {
    unsigned u = __float_as_uint(f);
    u += 0x7fffu + ((u >> 16) & 1u);   // round-nearest-even
    return (u16)(u >> 16);
}

// ---------------- CSR build ----------------

__global__ void count_k(const int* __restrict__ dst, int* __restrict__ counts, int ne) {
    int i = blockIdx.x * blockDim.x + threadIdx.x;
    if (i < ne) atomicAdd(&counts[dst[i]], 1);
}

// 3-pass blocked exclusive scan (verified r15)
__global__ __launch_bounds__(256) void scanA(const int* __restrict__ counts,
                                             int* __restrict__ bsum, int n) {
    __shared__ int ws[4];
    int blk = blockIdx.x, tid = threadIdx.x;
    int i0 = blk * 1024 + tid * 4;
    int s = 0;
#pragma unroll
    for (int j = 0; j < 4; j++) { int i = i0 + j; if (i < n) s += counts[i]; }
#pragma unroll
    for (int o = 1; o < 64; o <<= 1) s += __shfl_xor(s, o);
    int wv = tid >> 6, ln = tid & 63;
    if (ln == 0) ws[wv] = s;
    __syncthreads();
    if (tid == 0) bsum[blk] = ws[0] + ws[1] + ws[2] + ws[3];
}

__global__ __launch_bounds__(64) void scanB(int* __restrict__ bsum, int nb) {
    int ln = threadIdx.x;
    int carry = 0;
    for (int base = 0; base < nb; base += 64) {
        int i = base + ln;
        int v = (i < nb) ? bsum[i] : 0;
        int x = v;
#pragma unroll
        for (int o = 1; o < 64; o <<= 1) { int t = __shfl_up(x, o); if (ln >= o) x += t; }
        if (i < nb) bsum[i] = carry + x - v;   // exclusive
        carry += __shfl(x, 63);
    }
}

__global__ __launch_bounds__(256) void scanC(const int* __restrict__ counts,
                                             const int* __restrict__ bsum,
                                             int* __restrict__ offs, int* __restrict__ cursor,
                                             int n) {
    __shared__ int wtot[4];
    int blk = blockIdx.x, tid = threadIdx.x, wv = tid >> 6, ln = tid & 63;
    int i0 = blk * 1024 + tid * 4;
    int c[4]; int s = 0;
#pragma unroll
    for (int j = 0; j < 4; j++) { int i = i0 + j; c[j] = (i < n) ? counts[i] : 0; s += c[j]; }
    int x = s;
#pragma unroll
    for (int o = 1; o < 64; o <<= 1) { int t = __shfl_up(x, o); if (ln >= o) x += t; }
    if (ln == 63) wtot[wv] = x;
    int lpref = x - s;
    __syncthreads();
    int wbase = 0;
    for (int i = 0; i < wv; i++) wbase += wtot[i];
    int base = bsum[blk] + wbase + lpref;
#pragma unroll
    for (int j = 0; j < 4; j++) {
        int i = i0 + j;
        if (i < n) {
            offs[i] = base; cursor[i] = base; base += c[j];
            if (i == n - 1) offs[n] = base;
        }
    }
}

// scatter (src, ea) as ONE int2 per edge into CSR order
__global__ void fill_k(const int* __restrict__ src, const int* __restrict__ dst,
                       const float* __restrict__ ea, int* __restrict__ cursor,
                       int2* __restrict__ cedge, int ne) {
    int i = blockIdx.x * blockDim.x + threadIdx.x;
    if (i < ne) {
        int p = atomicAdd(&cursor[dst[i]], 1);
        int2 t;
        t.x = src[i];
        t.y = __float_as_int(ea[i]);
        cedge[p] = t;
    }
}

// ---------------- MFMA fragment packing ----------------

template <int KG>
__global__ void xpack_k(const float* __restrict__ X, short* __restrict__ Xp, int total) {
    int gid = blockIdx.x * blockDim.x + threadIdx.x;
    if (gid >= total) return;
    int lane = gid & 63;
    int kg = (gid >> 6) % KG;
    int rt = gid / (64 * KG);
    int row = rt * 16 + (lane & 15);
    int k0 = kg * 32 + ((lane >> 4) << 3);
    const float* src = X + (size_t)row * (KG * 32) + k0;
    short8v o;
#pragma unroll
    for (int j = 0; j < 8; j++) o[j] = (short)f2b(src[j]);
    ((short8v*)Xp)[gid] = o;
}

template <int K, int HOUT>
__global__ void packw_k(const float* __restrict__ Wl, const float* __restrict__ Wr,
                        short* __restrict__ Wp) {
    constexpr int KG = K / 32;
    int gid = blockIdx.x * blockDim.x + threadIdx.x;
    int lane = gid & 63;
    int kg = (gid >> 6) % KG;
    int nt = gid / (64 * KG);
    int col = nt * 16 + (lane & 15);
    int k0 = kg * 32 + ((lane >> 4) << 3);
    const float* Wsrc = (col < HOUT) ? Wl : Wr;
    int c2 = (col < HOUT) ? col : col - HOUT;
    short8v o;
#pragma unroll
    for (int j = 0; j < 8; j++) o[j] = (short)f2b(Wsrc[(size_t)(k0 + j) * HOUT + c2]);
    ((short8v*)Wp)[gid] = o;
}

// ---------------- MFMA GEMM (verified r7-15) + XCD mapping + coalesced LDS epilogue ----
// Each block owns ONE contiguous 128-col strip of XL or XR. Accumulators are staged
// through LDS (row stride 132 u16 -> conflict-free) and written 16B/thread, 256B/row.

template <int KG, int NT, int HOUT, int R>
__global__ __launch_bounds__(256) void gemm_mfma(
    const short* __restrict__ Xp, const short* __restrict__ Wp,
    const float* __restrict__ bl, const float* __restrict__ br,
    u16* __restrict__ XL, u16* __restrict__ XR, int nrt) {
    constexpr int NCG = NT / 8;
    __shared__ u16 ost[2][16][132];
    int w = threadIdx.x >> 6, lane = threadIdx.x & 63;
    int tid = threadIdx.x;
    int xcd = blockIdx.x & 7;
    int s = blockIdx.x >> 3;
    int cg = s % NCG;
    int rtg = xcd + 8 * (s / NCG);
    int rt0 = rtg * R;
    if (rt0 >= nrt) return;
    int rcnt = min(R, nrt - rt0);
    int nt0 = cg * 8 + w * 2;
    const short8v* wb = (const short8v*)Wp + lane;
    short8v wf0[KG], wf1[KG];
#pragma unroll
    for (int kg = 0; kg < KG; kg++) {
        wf0[kg] = wb[(size_t)(nt0 * KG + kg) * 64];
        wf1[kg] = wb[(size_t)((nt0 + 1) * KG + kg) * 64];
    }
    // block strip: cols cg*128 .. cg*128+127 of [XL|XR]
    int strip0 = cg * 128;
    bool isr = strip0 >= HOUT;
    int sb = strip0 - (isr ? HOUT : 0);
    u16* ob = (isr ? XR : XL) + sb;
    int cl0 = w * 32 + ((lane >> 4) << 2);   // col within strip (acc0)
    int cl1 = cl0 + 16;                      // acc1
    float4 bb0 = *(const float4*)((isr ? br : bl) + sb + cl0);
    float4 bb1 = *(const float4*)((isr ? br : bl) + sb + cl1);
    int orow = tid >> 4;                     // epilogue: row 0..15
    int ocol = (tid & 15) * 8;               // 8 u16 = 16B per thread

    const short8v* xb = (const short8v*)Xp + (size_t)rt0 * KG * 64 + lane;
    for (int r = 0; r < rcnt; ++r) {
        f32x4 acc0 = {0.f, 0.f, 0.f, 0.f}, acc1 = {0.f, 0.f, 0.f, 0.f};
#pragma unroll
        for (int kg = 0; kg < KG; kg++) {
            short8v xf = xb[(size_t)(r * KG + kg) * 64];
            acc0 = __builtin_amdgcn_mfma_f32_16x16x32_bf16(wf0[kg], xf, acc0, 0, 0, 0);
            acc1 = __builtin_amdgcn_mfma_f32_16x16x32_bf16(wf1[kg], xf, acc1, 0, 0, 0);
        }
        int b = r & 1;
        int row = lane & 15;
        u16* l0 = &ost[b][row][cl0];
        l0[0] = f2b(acc0[0] + bb0.x); l0[1] = f2b(acc0[1] + bb0.y);
        l0[2] = f2b(acc0[2] + bb0.z); l0[3] = f2b(acc0[3] + bb0.w);
        u16* l1 = &ost[b][row][cl1];
        l1[0] = f2b(acc1[0] + bb1.x); l1[1] = f2b(acc1[1] + bb1.y);
        l1[2] = f2b(acc1[2] + bb1.z); l1[3] = f2b(acc1[3] + bb1.w);
        __syncthreads();
        // coalesced write: 16 threads/row x 16B = 256B contiguous per row
        ushort4 v0 = *(ushort4*)&ost[b][orow][ocol];
        ushort4 v1 = *(ushort4*)&ost[b][orow][ocol + 4];
        u16* gp = ob + (size_t)((rt0 + r) * 16 + orow) * HOUT + ocol;
        *(ushort4*)gp = v0;
        *(ushort4*)(gp + 4) = v1;
    }
}

// ---------------- fused GATv2 layer (4 heads, C=64): WAVE-per-node, depth-5 prefetch ----

__global__ __launch_bounds__(256) void gat_fused4(
    const int* __restrict__ offs, const int2* __restrict__ cedge,
    const float* __restrict__ We, const float* __restrict__ att,
    const u16* __restrict__ XL, const u16* __restrict__ XR,
    const float* __restrict__ bo, const float* __restrict__ g, const float* __restrict__ be,
    u16* __restrict__ hp, int n) {
    __shared__ int   sS[4][64];
    __shared__ float sEA[4][64];
    int tid = threadIdx.x;
    int w = tid >> 6;
    int lane = tid & 63;
    int node = blockIdx.x * 4 + w;       // grid = n/4 exact
    int es = lane >> 5;
    int ls = lane & 31;
    int cabs = ls * 8;
    float xr[8], wev[8], atv[8];
    {
        short8v x8 = *(const short8v*)(XR + (size_t)node * 256 + cabs);
        float4 wA = *(const float4*)(We + cabs), wB = *(const float4*)(We + cabs + 4);
        float4 aA = *(const float4*)(att + cabs), aB = *(const float4*)(att + cabs + 4);
#pragma unroll
        for (int i = 0; i < 8; i++) xr[i] = b2f((u16)x8[i]);
        wev[0] = wA.x; wev[1] = wA.y; wev[2] = wA.z; wev[3] = wA.w;
        wev[4] = wB.x; wev[5] = wB.y; wev[6] = wB.z; wev[7] = wB.w;
        atv[0] = aA.x; atv[1] = aA.y; atv[2] = aA.z; atv[3] = aA.w;
        atv[4] = aB.x; atv[5] = aB.y; atv[6] = aB.z; atv[7] = aB.w;
    }
    int b0 = offs[node], eEnd = offs[node + 1];
    float dsum = 0.f;
    float acc[8];
#pragma unroll
    for (int i = 0; i < 8; i++) acc[i] = 0.f;
    for (int base = b0; base < eEnd; base += 64) {
        int cnt = min(64, eEnd - base);
        if (lane < cnt) {
            int2 t = cedge[base + lane];
            sS[w][lane] = t.x;
            sEA[w][lane] = __int_as_float(t.y);
        }
        // depth-5 rolling prefetch; this half's edges: es, es+2, es+4, ...
        short8v r0, r1, r2, r3, r4;
        float e0, e1f, e2, e3, e4;
        bool v0, v1, v2, v3, v4;
        {
            int j0 = es, j1 = es + 2, j2 = es + 4, j3 = es + 6, j4 = es + 8;
            v0 = j0 < cnt; v1 = j1 < cnt; v2 = j2 < cnt; v3 = j3 < cnt; v4 = j4 < cnt;
            int i0 = v0 ? j0 : 0, i1 = v1 ? j1 : 0, i2 = v2 ? j2 : 0;
            int i3 = v3 ? j3 : 0, i4 = v4 ? j4 : 0;
            e0 = sEA[w][i0]; r0 = *(const short8v*)(XL + (size_t)sS[w][i0] * 256 + cabs);
            e1f = sEA[w][i1]; r1 = *(const short8v*)(XL + (size_t)sS[w][i1] * 256 + cabs);
            e2 = sEA[w][i2]; r2 = *(const short8v*)(XL + (size_t)sS[w][i2] * 256 + cabs);
            e3 = sEA[w][i3]; r3 = *(const short8v*)(XL + (size_t)sS[w][i3] * 256 + cabs);
            e4 = sEA[w][i4]; r4 = *(const short8v*)(XL + (size_t)sS[w][i4] * 256 + cabs);
        }
        for (int r = 0; r < cnt; r += 2) {
            short8v rc = r0; float ec = e0; bool vc = v0;
            r0 = r1; e0 = e1f; v0 = v1;
            r1 = r2; e1f = e2; v1 = v2;
            r2 = r3; e2 = e3; v2 = v3;
            r3 = r4; e3 = e4; v3 = v4;
            int jn = r + 10 + es;
            v4 = jn < cnt;
            int idx = v4 ? jn : 0;
            e4 = sEA[w][idx];
            r4 = *(const short8v*)(XL + (size_t)sS[w][idx] * 256 + cabs);
            float x[8];
#pragma unroll
            for (int i = 0; i < 8; i++) x[i] = b2f((u16)rc[i]);
            float p = 0.f;
#pragma unroll
            for (int i = 0; i < 8; i++) {
                float t = fmaf(ec, wev[i], x[i]) + xr[i];
                t = fmaxf(t, 0.2f * t);
                p += t * atv[i];
            }
            p += __shfl_xor(p, 1);
            p += __shfl_xor(p, 2);
            p += __shfl_xor(p, 4);
            float wv2 = vc ? __expf(p) : 0.f;
            dsum += wv2;
#pragma unroll
            for (int i = 0; i < 8; i++) acc[i] += wv2 * x[i];
        }
    }
    dsum += __shfl_xor(dsum, 32);
#pragma unroll
    for (int i = 0; i < 8; i++) acc[i] += __shfl_xor(acc[i], 32);
    float inv = 1.f / (dsum + 1e-16f);
    float4 bA = *(const float4*)(bo + cabs), bB = *(const float4*)(bo + cabs + 4);
    float v[8];
    v[0] = acc[0] * inv + bA.x; v[1] = acc[1] * inv + bA.y;
    v[2] = acc[2] * inv + bA.z; v[3] = acc[3] * inv + bA.w;
    v[4] = acc[4] * inv + bB.x; v[5] = acc[5] * inv + bB.y;
    v[6] = acc[6] * inv + bB.z; v[7] = acc[7] * inv + bB.w;
    float s1 = 0.f, s2 = 0.f;
#pragma unroll
    for (int i = 0; i < 8; i++) { s1 += v[i]; s2 += v[i] * v[i]; }
#pragma unroll
    for (int o = 16; o >= 1; o >>= 1) {
        s1 += __shfl_xor(s1, o);
        s2 += __shfl_xor(s2, o);
    }
    float mu = s1 / 256.f;
    float sinv = rsqrtf(s2 / 256.f - mu * mu + 1e-5f);
    if (es == 0) {
        float4 gA = *(const float4*)(g + cabs), gB = *(const float4*)(g + cabs + 4);
        float4 eA = *(const float4*)(be + cabs), eB = *(const float4*)(be + cabs + 4);
        float gg[8] = {gA.x, gA.y, gA.z, gA.w, gB.x, gB.y, gB.z, gB.w};
        float ee[8] = {eA.x, eA.y, eA.z, eA.w, eB.x, eB.y, eB.z, eB.w};
        short8v yv;
#pragma unroll
        for (int i = 0; i < 8; i++) {
            float y = (v[i] - mu) * sinv * gg[i] + ee[i];
            y = (y > 0.f) ? y : expm1f(y);
            yv[i] = (short)f2b(y);
        }
        int kg = cabs >> 5;
        int l = (node & 15) | (((cabs >> 3) & 3) << 4);
        size_t eoff = (((size_t)(node >> 4) * 8 + kg) * 64 + l) * 8;
        *(short8v*)(hp + eoff) = yv;
    }
}

// ---------------- fused GATv2 layer (1 head, C=128): WAVE-per-node (CONTROL: unchanged) ----

__global__ __launch_bounds__(256) void gat_fused1(
    const int* __restrict__ offs, const int2* __restrict__ cedge,
    const float* __restrict__ We, const float* __restrict__ att,
    const u16* __restrict__ XL, const u16* __restrict__ XR,
    const float* __restrict__ bo, const float* __restrict__ g, const float* __restrict__ be,
    float* __restrict__ out, int n) {
    __shared__ int   sS[4][64];
    __shared__ float sEA[4][64];
    int tid = threadIdx.x;
    int w = tid >> 6;
    int lane = tid & 63;
    int node = blockIdx.x * 4 + w;       // grid = n/4 exact
    int q = lane >> 4;
    int ls = lane & 15;
    int cb = ls * 8;
    float xr[8], wev[8], atv[8];
    {
        short8v x8 = *(const short8v*)(XR + (size_t)node * 128 + cb);
        float4 wA = *(const float4*)(We + cb), wB = *(const float4*)(We + cb + 4);
        float4 aA = *(const float4*)(att + cb), aB = *(const float4*)(att + cb + 4);
#pragma unroll
        for (int i = 0; i < 8; i++) xr[i] = b2f((u16)x8[i]);
        wev[0] = wA.x; wev[1] = wA.y; wev[2] = wA.z; wev[3] = wA.w;
        wev[4] = wB.x; wev[5] = wB.y; wev[6] = wB.z; wev[7] = wB.w;
        atv[0] = aA.x; atv[1] = aA.y; atv[2] = aA.z; atv[3] = aA.w;
        atv[4] = aB.x; atv[5] = aB.y; atv[6] = aB.z; atv[7] = aB.w;
    }
    int b0 = offs[node], eEnd = offs[node + 1];
    float dsum = 0.f;
    float acc[8];
#pragma unroll
    for (int i = 0; i < 8; i++) acc[i] = 0.f;
    for (int base = b0; base < eEnd; base += 64) {
        int cnt = min(64, eEnd - base);
        if (lane < cnt) {
            int2 t = cedge[base + lane];
            sS[w][lane] = t.x;
            sEA[w][lane] = __int_as_float(t.y);
        }
        short8v r0, r1, r2;
        float e0, e1f, e2;
        bool v0, v1, v2;
        {
            int j0 = q, j1 = q + 4, j2 = q + 8;
            v0 = j0 < cnt; v1 = j1 < cnt; v2 = j2 < cnt;
            int i0 = v0 ? j0 : 0, i1 = v1 ? j1 : 0, i2 = v2 ? j2 : 0;
            e0 = sEA[w][i0]; r0 = *(const short8v*)(XL + (size_t)sS[w][i0] * 128 + cb);
            e1f = sEA[w][i1]; r1 = *(const short8v*)(XL + (size_t)sS[w][i1] * 128 + cb);
            e2 = sEA[w][i2]; r2 = *(const short8v*)(XL + (size_t)sS[w][i2] * 128 + cb);
        }
        for (int r = 0; r < cnt; r += 4) {
            short8v rc = r0; float ec = e0; bool vc = v0;
            r0 = r1; e0 = e1f; v0 = v1;
            r1 = r2; e1f = e2; v1 = v2;
            int jn = r + 12 + q;
            v2 = jn < cnt;
            int idx = v2 ? jn : 0;
            e2 = sEA[w][idx];
            r2 = *(const short8v*)(XL + (size_t)sS[w][idx] * 128 + cb);
            float x[8];
#pragma unroll
            for (int i = 0; i < 8; i++) x[i] = b2f((u16)rc[i]);
            float p = 0.f;
#pragma unroll
            for (int i = 0; i < 8; i++) {
                float t = fmaf(ec, wev[i], x[i]) + xr[i];
                t = fmaxf(t, 0.2f * t);
                p += t * atv[i];
            }
            p += __shfl_xor(p, 1);
            p += __shfl_xor(p, 2);
            p += __shfl_xor(p, 4);
            p += __shfl_xor(p, 8);
            float wv2 = vc ? __expf(p) : 0.f;
            dsum += wv2;
#pragma unroll
            for (int i = 0; i < 8; i++) acc[i] += wv2 * x[i];
        }
    }
    dsum += __shfl_xor(dsum, 32);
    dsum += __shfl_xor(dsum, 16);
#pragma unroll
    for (int i = 0; i < 8; i++) {
        acc[i] += __shfl_xor(acc[i], 32);
        acc[i] += __shfl_xor(acc[i], 16);
    }
    float inv = 1.f / (dsum + 1e-16f);
    float4 bA = *(const float4*)(bo + cb), bB = *(const float4*)(bo + cb + 4);
    float v[8];
    v[0] = acc[0] * inv + bA.x; v[1] = acc[1] * inv + bA.y;
    v[2] = acc[2] * inv + bA.z; v[3] = acc[3] * inv + bA.w;
    v[4] = acc[4] * inv + bB.x; v[5] = acc[5] * inv + bB.y;
    v[6] = acc[6] * inv + bB.z; v[7] = acc[7] * inv + bB.w;
    float s1 = 0.f, s2 = 0.f;
#pragma unroll
    for (int i = 0; i < 8; i++) { s1 += v[i]; s2 += v[i] * v[i]; }
#pragma unroll
    for (int o = 8; o >= 1; o >>= 1) {
        s1 += __shfl_xor(s1, o);
        s2 += __shfl_xor(s2, o);
    }
    float mu = s1 / 128.f;
    float sinv = rsqrtf(s2 / 128.f - mu * mu + 1e-5f);
    if (q == 0) {
        float4 gA = *(const float4*)(g + cb), gB = *(const float4*)(g + cb + 4);
        float4 eA = *(const float4*)(be + cb), eB = *(const float4*)(be + cb + 4);
        float gg[8] = {gA.x, gA.y, gA.z, gA.w, gB.x, gB.y, gB.z, gB.w};
        float ee[8] = {eA.x, eA.y, eA.z, eA.w, eB.x, eB.y, eB.z, eB.w};
        float4 oA, oB;
        oA.x = (v[0] - mu) * sinv * gg[0] + ee[0];
        oA.y = (v[1] - mu) * sinv * gg[1] + ee[1];
        oA.z = (v[2] - mu) * sinv * gg[2] + ee[2];
        oA.w = (v[3] - mu) * sinv * gg[3] + ee[3];
        oB.x = (v[4] - mu) * sinv * gg[4] + ee[4];
        oB.y = (v[5] - mu) * sinv * gg[5] + ee[5];
        oB.z = (v[6] - mu) * sinv * gg[6] + ee[6];
        oB.w = (v[7] - mu) * sinv * gg[7] + ee[7];
        float* op = out + (size_t)node * 128 + cb;
        *(float4*)op = oA;
        *(float4*)(op + 4) = oB;
    }
}

// ---------------- launcher ----------------

extern "C" void kernel_launch(void* const* d_in, const int* in_sizes, int n_in,
                              void* d_out, int out_size, void* d_ws, size_t ws_size,
                              hipStream_t stream) {
    const float* x  = (const float*)d_in[0];
    const int*   ei = (const int*)d_in[1];
    const float* ea = (const float*)d_in[2];
    const float *Wl1 = (const float*)d_in[3],  *bl1 = (const float*)d_in[4];
    const float *Wr1 = (const float*)d_in[5],  *br1 = (const float*)d_in[6];
    const float *We1 = (const float*)d_in[7],  *att1 = (const float*)d_in[8];
    const float *bo1 = (const float*)d_in[9],  *g1 = (const float*)d_in[10], *be1 = (const float*)d_in[11];
    const float *Wl2 = (const float*)d_in[12], *bl2 = (const float*)d_in[13];
    const float *Wr2 = (const float*)d_in[14], *br2 = (const float*)d_in[15];
    const float *We2 = (const float*)d_in[16], *att2 = (const float*)d_in[17];
    const float *bo2 = (const float*)d_in[18], *g2 = (const float*)d_in[19], *be2 = (const float*)d_in[20];
    const float *Wl3 = (const float*)d_in[21], *bl3 = (const float*)d_in[22];
    const float *Wr3 = (const float*)d_in[23], *br3 = (const float*)d_in[24];
    const float *We3 = (const float*)d_in[25], *att3 = (const float*)d_in[26];
    const float *bo3 = (const float*)d_in[27], *g3 = (const float*)d_in[28], *be3 = (const float*)d_in[29];

    int n = in_sizes[0] / IN_DIM;   // 50000
    int e = in_sizes[1] / 2;        // 800000
    const int* srcv = ei;
    const int* dstv = ei + e;
    int nrt = n / 16;               // 3125 row-tiles

    char* w = (char*)d_ws;
    size_t off = 0;
    auto take = [&](size_t bytes) -> void* {
        void* p = w + off;
        off = (off + bytes + 255) & ~(size_t)255;
        return p;
    };
    int*   counts = (int*)take((size_t)n * 4);
    int*   cursor = (int*)take((size_t)n * 4);
    int*   offs   = (int*)take((size_t)(n + 1) * 4);
    int*   bsum   = (int*)take(256 * 4);
    int2*  cedge  = (int2*)take((size_t)e * 8);
    u16*   XL     = (u16*)take((size_t)n * HID_DIM * 2);
    u16*   XR     = (u16*)take((size_t)n * HID_DIM * 2);
    short* xpack  = (short*)take((size_t)nrt * 4 * 64 * 8 * 2);   // K=128 fragments
    short* hpack  = (short*)take((size_t)nrt * 8 * 64 * 8 * 2);   // K=256 fragments
    short* wp1    = (short*)take((size_t)32 * 4 * 64 * 8 * 2);
    short* wp2    = (short*)take((size_t)32 * 8 * 64 * 8 * 2);
    short* wp3    = (short*)take((size_t)16 * 8 * 64 * 8 * 2);

    const int TPB = 256;
    int eb = (e + TPB - 1) / TPB;
    int nb = (n + 1023) / 1024;     // scan chunks

    // CSR build (shared by all 3 layers)
    hipMemsetAsync(counts, 0, (size_t)n * 4, stream);
    count_k<<<eb, TPB, 0, stream>>>(dstv, counts, e);
    scanA<<<nb, TPB, 0, stream>>>(counts, bsum, n);
    scanB<<<1, 64, 0, stream>>>(bsum, nb);
    scanC<<<nb, TPB, 0, stream>>>(counts, bsum, offs, cursor, n);
    fill_k<<<eb, TPB, 0, stream>>>(srcv, dstv, ea, cursor, cedge, e);

    // weight + input fragment packing
    packw_k<IN_DIM,  HID_DIM><<<32 * 4 * 64 / TPB, TPB, 0, stream>>>(Wl1, Wr1, wp1);
    packw_k<HID_DIM, HID_DIM><<<32 * 8 * 64 / TPB, TPB, 0, stream>>>(Wl2, Wr2, wp2);
    packw_k<HID_DIM, OUT_DIM><<<16 * 8 * 64 / TPB, TPB, 0, stream>>>(Wl3, Wr3, wp3);
    int xtot = nrt * 4 * 64;
    xpack_k<4><<<(xtot + TPB - 1) / TPB, TPB, 0, stream>>>(x, xpack, xtot);

    // XCD-aware GEMM grids: 8 * ceil(nrtg/8) * NCG
    int nrtg8 = (nrt + 7) / 8;                       // R=8 row-tile groups
    int grid12 = 8 * ((nrtg8 + 7) / 8) * 4;          // NCG=4
    int nrtg4 = (nrt + 3) / 4;                       // R=4
    int grid3 = 8 * ((nrtg4 + 7) / 8) * 2;           // NCG=2

    // ---- layer 1: GATv2(IN->HID, 4 heads) + LN + ELU ----
    gemm_mfma<4, 32, HID_DIM, 8><<<grid12, TPB, 0, stream>>>(
        xpack, wp1, bl1, br1, XL, XR, nrt);
    gat_fused4<<<n / 4, 256, 0, stream>>>(
        offs, cedge, We1, att1, XL, XR, bo1, g1, be1, (u16*)hpack, n);

    // ---- layer 2: GATv2(HID->HID, 4 heads) + LN + ELU ----
    gemm_mfma<8, 32, HID_DIM, 8><<<grid12, TPB, 0, stream>>>(
        hpack, wp2, bl2, br2, XL, XR, nrt);
    gat_fused4<<<n / 4, 256, 0, stream>>>(
        offs, cedge, We2, att2, XL, XR, bo2, g2, be2, (u16*)hpack, n);

    // ---- layer 3: GATv2(HID->OUT, 1 head) + LN ----
    gemm_mfma<8, 16, OUT_DIM, 4><<<grid3, TPB, 0, stream>>>(
        hpack, wp3, bl3, br3, XL, XR, nrt);
    gat_fused1<<<n / 4, 256, 0, stream>>>(
        offs, cedge, We3, att3, XL, XR, bo3, g3, be3, (float*)d_out, n);
}

// Round 17
// 390.896 us; speedup vs baseline: 1.0488x; 1.0488x over previous
//
#include <hip/hip_runtime.h>
#include <cstdint>
#include <cstddef>

typedef unsigned short u16;
typedef __attribute__((ext_vector_type(8))) short short8v;
typedef __attribute__((ext_vector_type(4))) float f32x4;

#define IN_DIM 128
#define HID_DIM 256
#define OUT_DIM 128
#define HEADS 4

__device__ __forceinline__ float b2f(u16 v) {
    return __uint_as_float(((unsigned)v) << 16);
}
__device__ __forceinline__ u16 f2b(float f) {
    unsigned u = __float_as_uint(f);
    u += 0x7fffu + ((u >> 16) & 1u);   // round-nearest-even
    return (u16)(u >> 16);
}

// ---------------- CSR build ----------------

__global__ void count_k(const int* __restrict__ dst, int* __restrict__ counts, int ne) {
    int i = blockIdx.x * blockDim.x + threadIdx.x;
    if (i < ne) atomicAdd(&counts[dst[i]], 1);
}

// 3-pass blocked exclusive scan (verified r15)
__global__ __launch_bounds__(256) void scanA(const int* __restrict__ counts,
                                             int* __restrict__ bsum, int n) {
    __shared__ int ws[4];
    int blk = blockIdx.x, tid = threadIdx.x;
    int i0 = blk * 1024 + tid * 4;
    int s = 0;
#pragma unroll
    for (int j = 0; j < 4; j++) { int i = i0 + j; if (i < n) s += counts[i]; }
#pragma unroll
    for (int o = 1; o < 64; o <<= 1) s += __shfl_xor(s, o);
    int wv = tid >> 6, ln = tid & 63;
    if (ln == 0) ws[wv] = s;
    __syncthreads();
    if (tid == 0) bsum[blk] = ws[0] + ws[1] + ws[2] + ws[3];
}

__global__ __launch_bounds__(64) void scanB(int* __restrict__ bsum, int nb) {
    int ln = threadIdx.x;
    int carry = 0;
    for (int base = 0; base < nb; base += 64) {
        int i = base + ln;
        int v = (i < nb) ? bsum[i] : 0;
        int x = v;
#pragma unroll
        for (int o = 1; o < 64; o <<= 1) { int t = __shfl_up(x, o); if (ln >= o) x += t; }
        if (i < nb) bsum[i] = carry + x - v;   // exclusive
        carry += __shfl(x, 63);
    }
}

__global__ __launch_bounds__(256) void scanC(const int* __restrict__ counts,
                                             const int* __restrict__ bsum,
                                             int* __restrict__ offs, int* __restrict__ cursor,
                                             int n) {
    __shared__ int wtot[4];
    int blk = blockIdx.x, tid = threadIdx.x, wv = tid >> 6, ln = tid & 63;
    int i0 = blk * 1024 + tid * 4;
    int c[4]; int s = 0;
#pragma unroll
    for (int j = 0; j < 4; j++) { int i = i0 + j; c[j] = (i < n) ? counts[i] : 0; s += c[j]; }
    int x = s;
#pragma unroll
    for (int o = 1; o < 64; o <<= 1) { int t = __shfl_up(x, o); if (ln >= o) x += t; }
    if (ln == 63) wtot[wv] = x;
    int lpref = x - s;
    __syncthreads();
    int wbase = 0;
    for (int i = 0; i < wv; i++) wbase += wtot[i];
    int base = bsum[blk] + wbase + lpref;
#pragma unroll
    for (int j = 0; j < 4; j++) {
        int i = i0 + j;
        if (i < n) {
            offs[i] = base; cursor[i] = base; base += c[j];
            if (i == n - 1) offs[n] = base;
        }
    }
}

// scatter (src, ea) as ONE int2 per edge into CSR order
__global__ void fill_k(const int* __restrict__ src, const int* __restrict__ dst,
                       const float* __restrict__ ea, int* __restrict__ cursor,
                       int2* __restrict__ cedge, int ne) {
    int i = blockIdx.x * blockDim.x + threadIdx.x;
    if (i < ne) {
        int p = atomicAdd(&cursor[dst[i]], 1);
        int2 t;
        t.x = src[i];
        t.y = __float_as_int(ea[i]);
        cedge[p] = t;
    }
}

// ---------------- MFMA fragment packing ----------------

template <int KG>
__global__ void xpack_k(const float* __restrict__ X, short* __restrict__ Xp, int total) {
    int gid = blockIdx.x * blockDim.x + threadIdx.x;
    if (gid >= total) return;
    int lane = gid & 63;
    int kg = (gid >> 6) % KG;
    int rt = gid / (64 * KG);
    int row = rt * 16 + (lane & 15);
    int k0 = kg * 32 + ((lane >> 4) << 3);
    const float* src = X + (size_t)row * (KG * 32) + k0;
    short8v o;
#pragma unroll
    for (int j = 0; j < 8; j++) o[j] = (short)f2b(src[j]);
    ((short8v*)Xp)[gid] = o;
}

template <int K, int HOUT>
__global__ void packw_k(const float* __restrict__ Wl, const float* __restrict__ Wr,
                        short* __restrict__ Wp) {
    constexpr int KG = K / 32;
    int gid = blockIdx.x * blockDim.x + threadIdx.x;
    int lane = gid & 63;
    int kg = (gid >> 6) % KG;
    int nt = gid / (64 * KG);
    int col = nt * 16 + (lane & 15);
    int k0 = kg * 32 + ((lane >> 4) << 3);
    const float* Wsrc = (col < HOUT) ? Wl : Wr;
    int c2 = (col < HOUT) ? col : col - HOUT;
    short8v o;
#pragma unroll
    for (int j = 0; j < 8; j++) o[j] = (short)f2b(Wsrc[(size_t)(k0 + j) * HOUT + c2]);
    ((short8v*)Wp)[gid] = o;
}

// ---------------- MFMA GEMM (verified r16) + XCD mapping + coalesced LDS epilogue ----

template <int KG, int NT, int HOUT, int R>
__global__ __launch_bounds__(256) void gemm_mfma(
    const short* __restrict__ Xp, const short* __restrict__ Wp,
    const float* __restrict__ bl, const float* __restrict__ br,
    u16* __restrict__ XL, u16* __restrict__ XR, int nrt) {
    constexpr int NCG = NT / 8;
    __shared__ u16 ost[2][16][132];
    int w = threadIdx.x >> 6, lane = threadIdx.x & 63;
    int tid = threadIdx.x;
    int xcd = blockIdx.x & 7;
    int s = blockIdx.x >> 3;
    int cg = s % NCG;
    int rtg = xcd + 8 * (s / NCG);
    int rt0 = rtg * R;
    if (rt0 >= nrt) return;
    int rcnt = min(R, nrt - rt0);
    int nt0 = cg * 8 + w * 2;
    const short8v* wb = (const short8v*)Wp + lane;
    short8v wf0[KG], wf1[KG];
#pragma unroll
    for (int kg = 0; kg < KG; kg++) {
        wf0[kg] = wb[(size_t)(nt0 * KG + kg) * 64];
        wf1[kg] = wb[(size_t)((nt0 + 1) * KG + kg) * 64];
    }
    // block strip: cols cg*128 .. cg*128+127 of [XL|XR]
    int strip0 = cg * 128;
    bool isr = strip0 >= HOUT;
    int sb = strip0 - (isr ? HOUT : 0);
    u16* ob = (isr ? XR : XL) + sb;
    int cl0 = w * 32 + ((lane >> 4) << 2);   // col within strip (acc0)
    int cl1 = cl0 + 16;                      // acc1
    float4 bb0 = *(const float4*)((isr ? br : bl) + sb + cl0);
    float4 bb1 = *(const float4*)((isr ? br : bl) + sb + cl1);
    int orow = tid >> 4;                     // epilogue: row 0..15
    int ocol = (tid & 15) * 8;               // 8 u16 = 16B per thread

    const short8v* xb = (const short8v*)Xp + (size_t)rt0 * KG * 64 + lane;
    for (int r = 0; r < rcnt; ++r) {
        f32x4 acc0 = {0.f, 0.f, 0.f, 0.f}, acc1 = {0.f, 0.f, 0.f, 0.f};
#pragma unroll
        for (int kg = 0; kg < KG; kg++) {
            short8v xf = xb[(size_t)(r * KG + kg) * 64];
            acc0 = __builtin_amdgcn_mfma_f32_16x16x32_bf16(wf0[kg], xf, acc0, 0, 0, 0);
            acc1 = __builtin_amdgcn_mfma_f32_16x16x32_bf16(wf1[kg], xf, acc1, 0, 0, 0);
        }
        int b = r & 1;
        int row = lane & 15;
        u16* l0 = &ost[b][row][cl0];
        l0[0] = f2b(acc0[0] + bb0.x); l0[1] = f2b(acc0[1] + bb0.y);
        l0[2] = f2b(acc0[2] + bb0.z); l0[3] = f2b(acc0[3] + bb0.w);
        u16* l1 = &ost[b][row][cl1];
        l1[0] = f2b(acc1[0] + bb1.x); l1[1] = f2b(acc1[1] + bb1.y);
        l1[2] = f2b(acc1[2] + bb1.z); l1[3] = f2b(acc1[3] + bb1.w);
        __syncthreads();
        // coalesced write: 16 threads/row x 16B = 256B contiguous per row
        ushort4 v0 = *(ushort4*)&ost[b][orow][ocol];
        ushort4 v1 = *(ushort4*)&ost[b][orow][ocol + 4];
        u16* gp = ob + (size_t)((rt0 + r) * 16 + orow) * HOUT + ocol;
        *(ushort4*)gp = v0;
        *(ushort4*)(gp + 4) = v1;
    }
}

// ---------------- fused GATv2 layer (4 heads, C=64): WAVE-per-node, depth-3 (verified r14) ----

__global__ __launch_bounds__(256) void gat_fused4(
    const int* __restrict__ offs, const int2* __restrict__ cedge,
    const float* __restrict__ We, const float* __restrict__ att,
    const u16* __restrict__ XL, const u16* __restrict__ XR,
    const float* __restrict__ bo, const float* __restrict__ g, const float* __restrict__ be,
    u16* __restrict__ hp, int n) {
    __shared__ int   sS[4][64];
    __shared__ float sEA[4][64];
    int tid = threadIdx.x;
    int w = tid >> 6;
    int lane = tid & 63;
    int node = blockIdx.x * 4 + w;       // grid = n/4 exact
    int es = lane >> 5;
    int ls = lane & 31;
    int cabs = ls * 8;
    float xr[8], wev[8], atv[8];
    {
        short8v x8 = *(const short8v*)(XR + (size_t)node * 256 + cabs);
        float4 wA = *(const float4*)(We + cabs), wB = *(const float4*)(We + cabs + 4);
        float4 aA = *(const float4*)(att + cabs), aB = *(const float4*)(att + cabs + 4);
#pragma unroll
        for (int i = 0; i < 8; i++) xr[i] = b2f((u16)x8[i]);
        wev[0] = wA.x; wev[1] = wA.y; wev[2] = wA.z; wev[3] = wA.w;
        wev[4] = wB.x; wev[5] = wB.y; wev[6] = wB.z; wev[7] = wB.w;
        atv[0] = aA.x; atv[1] = aA.y; atv[2] = aA.z; atv[3] = aA.w;
        atv[4] = aB.x; atv[5] = aB.y; atv[6] = aB.z; atv[7] = aB.w;
    }
    int b0 = offs[node], eEnd = offs[node + 1];
    float dsum = 0.f;
    float acc[8];
#pragma unroll
    for (int i = 0; i < 8; i++) acc[i] = 0.f;
    for (int base = b0; base < eEnd; base += 64) {
        int cnt = min(64, eEnd - base);
        if (lane < cnt) {
            int2 t = cedge[base + lane];
            sS[w][lane] = t.x;
            sEA[w][lane] = __int_as_float(t.y);
        }
        short8v r0, r1, r2;
        float e0, e1f, e2;
        bool v0, v1, v2;
        {
            int j0 = es, j1 = es + 2, j2 = es + 4;
            v0 = j0 < cnt; v1 = j1 < cnt; v2 = j2 < cnt;
            int i0 = v0 ? j0 : 0, i1 = v1 ? j1 : 0, i2 = v2 ? j2 : 0;
            e0 = sEA[w][i0]; r0 = *(const short8v*)(XL + (size_t)sS[w][i0] * 256 + cabs);
            e1f = sEA[w][i1]; r1 = *(const short8v*)(XL + (size_t)sS[w][i1] * 256 + cabs);
            e2 = sEA[w][i2]; r2 = *(const short8v*)(XL + (size_t)sS[w][i2] * 256 + cabs);
        }
        for (int r = 0; r < cnt; r += 2) {
            short8v rc = r0; float ec = e0; bool vc = v0;
            r0 = r1; e0 = e1f; v0 = v1;
            r1 = r2; e1f = e2; v1 = v2;
            int jn = r + 6 + es;
            v2 = jn < cnt;
            int idx = v2 ? jn : 0;
            e2 = sEA[w][idx];
            r2 = *(const short8v*)(XL + (size_t)sS[w][idx] * 256 + cabs);
            float x[8];
#pragma unroll
            for (int i = 0; i < 8; i++) x[i] = b2f((u16)rc[i]);
            float p = 0.f;
#pragma unroll
            for (int i = 0; i < 8; i++) {
                float t = fmaf(ec, wev[i], x[i]) + xr[i];
                t = fmaxf(t, 0.2f * t);
                p += t * atv[i];
            }
            p += __shfl_xor(p, 1);
            p += __shfl_xor(p, 2);
            p += __shfl_xor(p, 4);
            float wv2 = vc ? __expf(p) : 0.f;
            dsum += wv2;
#pragma unroll
            for (int i = 0; i < 8; i++) acc[i] += wv2 * x[i];
        }
    }
    dsum += __shfl_xor(dsum, 32);
#pragma unroll
    for (int i = 0; i < 8; i++) acc[i] += __shfl_xor(acc[i], 32);
    float inv = 1.f / (dsum + 1e-16f);
    float4 bA = *(const float4*)(bo + cabs), bB = *(const float4*)(bo + cabs + 4);
    float v[8];
    v[0] = acc[0] * inv + bA.x; v[1] = acc[1] * inv + bA.y;
    v[2] = acc[2] * inv + bA.z; v[3] = acc[3] * inv + bA.w;
    v[4] = acc[4] * inv + bB.x; v[5] = acc[5] * inv + bB.y;
    v[6] = acc[6] * inv + bB.z; v[7] = acc[7] * inv + bB.w;
    float s1 = 0.f, s2 = 0.f;
#pragma unroll
    for (int i = 0; i < 8; i++) { s1 += v[i]; s2 += v[i] * v[i]; }
#pragma unroll
    for (int o = 16; o >= 1; o >>= 1) {
        s1 += __shfl_xor(s1, o);
        s2 += __shfl_xor(s2, o);
    }
    float mu = s1 / 256.f;
    float sinv = rsqrtf(s2 / 256.f - mu * mu + 1e-5f);
    if (es == 0) {
        float4 gA = *(const float4*)(g + cabs), gB = *(const float4*)(g + cabs + 4);
        float4 eA = *(const float4*)(be + cabs), eB = *(const float4*)(be + cabs + 4);
        float gg[8] = {gA.x, gA.y, gA.z, gA.w, gB.x, gB.y, gB.z, gB.w};
        float ee[8] = {eA.x, eA.y, eA.z, eA.w, eB.x, eB.y, eB.z, eB.w};
        short8v yv;
#pragma unroll
        for (int i = 0; i < 8; i++) {
            float y = (v[i] - mu) * sinv * gg[i] + ee[i];
            y = (y > 0.f) ? y : expm1f(y);
            yv[i] = (short)f2b(y);
        }
        int kg = cabs >> 5;
        int l = (node & 15) | (((cabs >> 3) & 3) << 4);
        size_t eoff = (((size_t)(node >> 4) * 8 + kg) * 64 + l) * 8;
        *(short8v*)(hp + eoff) = yv;
    }
}

// ---------------- fused GATv2 layer (1 head, C=128): WAVE-per-node (verified r12-15) ----

__global__ __launch_bounds__(256) void gat_fused1(
    const int* __restrict__ offs, const int2* __restrict__ cedge,
    const float* __restrict__ We, const float* __restrict__ att,
    const u16* __restrict__ XL, const u16* __restrict__ XR,
    const float* __restrict__ bo, const float* __restrict__ g, const float* __restrict__ be,
    float* __restrict__ out, int n) {
    __shared__ int   sS[4][64];
    __shared__ float sEA[4][64];
    int tid = threadIdx.x;
    int w = tid >> 6;
    int lane = tid & 63;
    int node = blockIdx.x * 4 + w;       // grid = n/4 exact
    int q = lane >> 4;
    int ls = lane & 15;
    int cb = ls * 8;
    float xr[8], wev[8], atv[8];
    {
        short8v x8 = *(const short8v*)(XR + (size_t)node * 128 + cb);
        float4 wA = *(const float4*)(We + cb), wB = *(const float4*)(We + cb + 4);
        float4 aA = *(const float4*)(att + cb), aB = *(const float4*)(att + cb + 4);
#pragma unroll
        for (int i = 0; i < 8; i++) xr[i] = b2f((u16)x8[i]);
        wev[0] = wA.x; wev[1] = wA.y; wev[2] = wA.z; wev[3] = wA.w;
        wev[4] = wB.x; wev[5] = wB.y; wev[6] = wB.z; wev[7] = wB.w;
        atv[0] = aA.x; atv[1] = aA.y; atv[2] = aA.z; atv[3] = aA.w;
        atv[4] = aB.x; atv[5] = aB.y; atv[6] = aB.z; atv[7] = aB.w;
    }
    int b0 = offs[node], eEnd = offs[node + 1];
    float dsum = 0.f;
    float acc[8];
#pragma unroll
    for (int i = 0; i < 8; i++) acc[i] = 0.f;
    for (int base = b0; base < eEnd; base += 64) {
        int cnt = min(64, eEnd - base);
        if (lane < cnt) {
            int2 t = cedge[base + lane];
            sS[w][lane] = t.x;
            sEA[w][lane] = __int_as_float(t.y);
        }
        short8v r0, r1, r2;
        float e0, e1f, e2;
        bool v0, v1, v2;
        {
            int j0 = q, j1 = q + 4, j2 = q + 8;
            v0 = j0 < cnt; v1 = j1 < cnt; v2 = j2 < cnt;
            int i0 = v0 ? j0 : 0, i1 = v1 ? j1 : 0, i2 = v2 ? j2 : 0;
            e0 = sEA[w][i0]; r0 = *(const short8v*)(XL + (size_t)sS[w][i0] * 128 + cb);
            e1f = sEA[w][i1]; r1 = *(const short8v*)(XL + (size_t)sS[w][i1] * 128 + cb);
            e2 = sEA[w][i2]; r2 = *(const short8v*)(XL + (size_t)sS[w][i2] * 128 + cb);
        }
        for (int r = 0; r < cnt; r += 4) {
            short8v rc = r0; float ec = e0; bool vc = v0;
            r0 = r1; e0 = e1f; v0 = v1;
            r1 = r2; e1f = e2; v1 = v2;
            int jn = r + 12 + q;
            v2 = jn < cnt;
            int idx = v2 ? jn : 0;
            e2 = sEA[w][idx];
            r2 = *(const short8v*)(XL + (size_t)sS[w][idx] * 128 + cb);
            float x[8];
#pragma unroll
            for (int i = 0; i < 8; i++) x[i] = b2f((u16)rc[i]);
            float p = 0.f;
#pragma unroll
            for (int i = 0; i < 8; i++) {
                float t = fmaf(ec, wev[i], x[i]) + xr[i];
                t = fmaxf(t, 0.2f * t);
                p += t * atv[i];
            }
            p += __shfl_xor(p, 1);
            p += __shfl_xor(p, 2);
            p += __shfl_xor(p, 4);
            p += __shfl_xor(p, 8);
            float wv2 = vc ? __expf(p) : 0.f;
            dsum += wv2;
#pragma unroll
            for (int i = 0; i < 8; i++) acc[i] += wv2 * x[i];
        }
    }
    dsum += __shfl_xor(dsum, 32);
    dsum += __shfl_xor(dsum, 16);
#pragma unroll
    for (int i = 0; i < 8; i++) {
        acc[i] += __shfl_xor(acc[i], 32);
        acc[i] += __shfl_xor(acc[i], 16);
    }
    float inv = 1.f / (dsum + 1e-16f);
    float4 bA = *(const float4*)(bo + cb), bB = *(const float4*)(bo + cb + 4);
    float v[8];
    v[0] = acc[0] * inv + bA.x; v[1] = acc[1] * inv + bA.y;
    v[2] = acc[2] * inv + bA.z; v[3] = acc[3] * inv + bA.w;
    v[4] = acc[4] * inv + bB.x; v[5] = acc[5] * inv + bB.y;
    v[6] = acc[6] * inv + bB.z; v[7] = acc[7] * inv + bB.w;
    float s1 = 0.f, s2 = 0.f;
#pragma unroll
    for (int i = 0; i < 8; i++) { s1 += v[i]; s2 += v[i] * v[i]; }
#pragma unroll
    for (int o = 8; o >= 1; o >>= 1) {
        s1 += __shfl_xor(s1, o);
        s2 += __shfl_xor(s2, o);
    }
    float mu = s1 / 128.f;
    float sinv = rsqrtf(s2 / 128.f - mu * mu + 1e-5f);
    if (q == 0) {
        float4 gA = *(const float4*)(g + cb), gB = *(const float4*)(g + cb + 4);
        float4 eA = *(const float4*)(be + cb), eB = *(const float4*)(be + cb + 4);
        float gg[8] = {gA.x, gA.y, gA.z, gA.w, gB.x, gB.y, gB.z, gB.w};
        float ee[8] = {eA.x, eA.y, eA.z, eA.w, eB.x, eB.y, eB.z, eB.w};
        float4 oA, oB;
        oA.x = (v[0] - mu) * sinv * gg[0] + ee[0];
        oA.y = (v[1] - mu) * sinv * gg[1] + ee[1];
        oA.z = (v[2] - mu) * sinv * gg[2] + ee[2];
        oA.w = (v[3] - mu) * sinv * gg[3] + ee[3];
        oB.x = (v[4] - mu) * sinv * gg[4] + ee[4];
        oB.y = (v[5] - mu) * sinv * gg[5] + ee[5];
        oB.z = (v[6] - mu) * sinv * gg[6] + ee[6];
        oB.w = (v[7] - mu) * sinv * gg[7] + ee[7];
        float* op = out + (size_t)node * 128 + cb;
        *(float4*)op = oA;
        *(float4*)(op + 4) = oB;
    }
}

// ---------------- launcher ----------------

extern "C" void kernel_launch(void* const* d_in, const int* in_sizes, int n_in,
                              void* d_out, int out_size, void* d_ws, size_t ws_size,
                              hipStream_t stream) {
    const float* x  = (const float*)d_in[0];
    const int*   ei = (const int*)d_in[1];
    const float* ea = (const float*)d_in[2];
    const float *Wl1 = (const float*)d_in[3],  *bl1 = (const float*)d_in[4];
    const float *Wr1 = (const float*)d_in[5],  *br1 = (const float*)d_in[6];
    const float *We1 = (const float*)d_in[7],  *att1 = (const float*)d_in[8];
    const float *bo1 = (const float*)d_in[9],  *g1 = (const float*)d_in[10], *be1 = (const float*)d_in[11];
    const float *Wl2 = (const float*)d_in[12], *bl2 = (const float*)d_in[13];
    const float *Wr2 = (const float*)d_in[14], *br2 = (const float*)d_in[15];
    const float *We2 = (const float*)d_in[16], *att2 = (const float*)d_in[17];
    const float *bo2 = (const float*)d_in[18], *g2 = (const float*)d_in[19], *be2 = (const float*)d_in[20];
    const float *Wl3 = (const float*)d_in[21], *bl3 = (const float*)d_in[22];
    const float *Wr3 = (const float*)d_in[23], *br3 = (const float*)d_in[24];
    const float *We3 = (const float*)d_in[25], *att3 = (const float*)d_in[26];
    const float *bo3 = (const float*)d_in[27], *g3 = (const float*)d_in[28], *be3 = (const float*)d_in[29];

    int n = in_sizes[0] / IN_DIM;   // 50000
    int e = in_sizes[1] / 2;        // 800000
    const int* srcv = ei;
    const int* dstv = ei + e;
    int nrt = n / 16;               // 3125 row-tiles

    char* w = (char*)d_ws;
    size_t off = 0;
    auto take = [&](size_t bytes) -> void* {
        void* p = w + off;
        off = (off + bytes + 255) & ~(size_t)255;
        return p;
    };
    int*   counts = (int*)take((size_t)n * 4);
    int*   cursor = (int*)take((size_t)n * 4);
    int*   offs   = (int*)take((size_t)(n + 1) * 4);
    int*   bsum   = (int*)take(256 * 4);
    int2*  cedge  = (int2*)take((size_t)e * 8);
    u16*   XL     = (u16*)take((size_t)n * HID_DIM * 2);
    u16*   XR     = (u16*)take((size_t)n * HID_DIM * 2);
    short* xpack  = (short*)take((size_t)nrt * 4 * 64 * 8 * 2);   // K=128 fragments
    short* hpack  = (short*)take((size_t)nrt * 8 * 64 * 8 * 2);   // K=256 fragments
    short* wp1    = (short*)take((size_t)32 * 4 * 64 * 8 * 2);
    short* wp2    = (short*)take((size_t)32 * 8 * 64 * 8 * 2);
    short* wp3    = (short*)take((size_t)16 * 8 * 64 * 8 * 2);

    const int TPB = 256;
    int eb = (e + TPB - 1) / TPB;
    int nb = (n + 1023) / 1024;     // scan chunks

    // CSR build (shared by all 3 layers)
    hipMemsetAsync(counts, 0, (size_t)n * 4, stream);
    count_k<<<eb, TPB, 0, stream>>>(dstv, counts, e);
    scanA<<<nb, TPB, 0, stream>>>(counts, bsum, n);
    scanB<<<1, 64, 0, stream>>>(bsum, nb);
    scanC<<<nb, TPB, 0, stream>>>(counts, bsum, offs, cursor, n);
    fill_k<<<eb, TPB, 0, stream>>>(srcv, dstv, ea, cursor, cedge, e);

    // weight + input fragment packing
    packw_k<IN_DIM,  HID_DIM><<<32 * 4 * 64 / TPB, TPB, 0, stream>>>(Wl1, Wr1, wp1);
    packw_k<HID_DIM, HID_DIM><<<32 * 8 * 64 / TPB, TPB, 0, stream>>>(Wl2, Wr2, wp2);
    packw_k<HID_DIM, OUT_DIM><<<16 * 8 * 64 / TPB, TPB, 0, stream>>>(Wl3, Wr3, wp3);
    int xtot = nrt * 4 * 64;
    xpack_k<4><<<(xtot + TPB - 1) / TPB, TPB, 0, stream>>>(x, xpack, xtot);

    // XCD-aware GEMM grids: 8 * ceil(nrtg/8) * NCG
    int nrtg8 = (nrt + 7) / 8;                       // R=8 row-tile groups
    int grid12 = 8 * ((nrtg8 + 7) / 8) * 4;          // NCG=4
    int nrtg4 = (nrt + 3) / 4;                       // R=4
    int grid3 = 8 * ((nrtg4 + 7) / 8) * 2;           // NCG=2

    // ---- layer 1: GATv2(IN->HID, 4 heads) + LN + ELU ----
    gemm_mfma<4, 32, HID_DIM, 8><<<grid12, TPB, 0, stream>>>(
        xpack, wp1, bl1, br1, XL, XR, nrt);
    gat_fused4<<<n / 4, 256, 0, stream>>>(
        offs, cedge, We1, att1, XL, XR, bo1, g1, be1, (u16*)hpack, n);

    // ---- layer 2: GATv2(HID->HID, 4 heads) + LN + ELU ----
    gemm_mfma<8, 32, HID_DIM, 8><<<grid12, TPB, 0, stream>>>(
        hpack, wp2, bl2, br2, XL, XR, nrt);
    gat_fused4<<<n / 4, 256, 0, stream>>>(
        offs, cedge, We2, att2, XL, XR, bo2, g2, be2, (u16*)hpack, n);

    // ---- layer 3: GATv2(HID->OUT, 1 head) + LN ----
    gemm_mfma<8, 16, OUT_DIM, 4><<<grid3, TPB, 0, stream>>>(
        hpack, wp3, bl3, br3, XL, XR, nrt);
    gat_fused1<<<n / 4, 256, 0, stream>>>(
        offs, cedge, We3, att3, XL, XR, bo3, g3, be3, (float*)d_out, n);
}